// Round 1
// baseline (9907.983 us; speedup 1.0000x reference)
//
#include <hip/hip_runtime.h>
#include <hip/hip_bf16.h>
#include <math.h>

// Problem constants
#define B 64
#define S 64
#define T 15
#define H 1024
#define V 50257
// SOS token = 0

#define BM 64
#define BN 64
#define BK 16

// Generic fp32 GEMM: C[M,N] = A[M,K] @ Bt[N,K]^T + bias[N]
// M must be a multiple of 64; K a multiple of 16; N can be ragged.
__global__ __launch_bounds__(256) void gemm_abt(
    const float* __restrict__ A, const float* __restrict__ Bt,
    const float* __restrict__ bias, float* __restrict__ C,
    int M, int N, int K) {
  __shared__ float As[BK][BM + 4];
  __shared__ float Bs[BK][BN + 4];
  const int tid  = threadIdx.x;
  const int bm   = blockIdx.y * BM;
  const int bn   = blockIdx.x * BN;
  const int lrow = tid >> 2;         // 0..63
  const int lcol = (tid & 3) << 2;   // 0,4,8,12
  const int ty   = tid >> 4;         // 0..15
  const int tx   = tid & 15;         // 0..15

  float acc[4][4] = {};

  const float* Arow = A + (size_t)(bm + lrow) * K;
  const int    brow = bn + lrow;
  const float* Brow = Bt + (size_t)brow * K;
  const bool bvalid = (brow < N);

  for (int k0 = 0; k0 < K; k0 += BK) {
    float4 av = *(const float4*)(Arow + k0 + lcol);
    As[lcol + 0][lrow] = av.x;
    As[lcol + 1][lrow] = av.y;
    As[lcol + 2][lrow] = av.z;
    As[lcol + 3][lrow] = av.w;
    float4 bv4 = bvalid ? *(const float4*)(Brow + k0 + lcol)
                        : make_float4(0.f, 0.f, 0.f, 0.f);
    Bs[lcol + 0][lrow] = bv4.x;
    Bs[lcol + 1][lrow] = bv4.y;
    Bs[lcol + 2][lrow] = bv4.z;
    Bs[lcol + 3][lrow] = bv4.w;
    __syncthreads();
#pragma unroll
    for (int k = 0; k < BK; ++k) {
      float a0 = As[k][ty * 4 + 0];
      float a1 = As[k][ty * 4 + 1];
      float a2 = As[k][ty * 4 + 2];
      float a3 = As[k][ty * 4 + 3];
      float b0 = Bs[k][tx * 4 + 0];
      float b1 = Bs[k][tx * 4 + 1];
      float b2 = Bs[k][tx * 4 + 2];
      float b3 = Bs[k][tx * 4 + 3];
      acc[0][0] += a0 * b0; acc[0][1] += a0 * b1; acc[0][2] += a0 * b2; acc[0][3] += a0 * b3;
      acc[1][0] += a1 * b0; acc[1][1] += a1 * b1; acc[1][2] += a1 * b2; acc[1][3] += a1 * b3;
      acc[2][0] += a2 * b0; acc[2][1] += a2 * b1; acc[2][2] += a2 * b2; acc[2][3] += a2 * b3;
      acc[3][0] += a3 * b0; acc[3][1] += a3 * b1; acc[3][2] += a3 * b2; acc[3][3] += a3 * b3;
    }
    __syncthreads();
  }

#pragma unroll
  for (int i = 0; i < 4; ++i) {
    int m = bm + ty * 4 + i;
#pragma unroll
    for (int j = 0; j < 4; ++j) {
      int n = bn + tx * 4 + j;
      if (n < N) {
        C[(size_t)m * N + n] = acc[i][j] + (bias ? bias[n] : 0.f);
      }
    }
  }
}

// Attention for one decode step. One block per batch row b.
// scores[s] = Va . tanh(q[b] + Uk[b,s]) + bv ; w = softmax(scores)
// ctx[b] = sum_s w[s] * enc[b,s,:] ; also writes attentions out[b,t,:].
__global__ __launch_bounds__(256) void attn_kernel(
    const float* __restrict__ q, const float* __restrict__ Uk,
    const float* __restrict__ Va, const float* __restrict__ bv,
    const float* __restrict__ enc, float* __restrict__ ctx,
    float* __restrict__ attn_out, int t) {
  __shared__ float qs[H];
  __shared__ float vas[H];
  __shared__ float sc[S];
  const int b   = blockIdx.x;
  const int tid = threadIdx.x;

  for (int i = tid; i < H; i += 256) {
    qs[i]  = q[(size_t)b * H + i];
    vas[i] = Va[i];
  }
  __syncthreads();

  const int wave = tid >> 6;
  const int lane = tid & 63;
  for (int s = wave; s < S; s += 4) {
    const float* uk = Uk + ((size_t)(b * S + s)) * H;
    float sum = 0.f;
    for (int h = lane; h < H; h += 64) {
      sum += vas[h] * tanhf(qs[h] + uk[h]);
    }
#pragma unroll
    for (int off = 32; off > 0; off >>= 1) sum += __shfl_down(sum, off);
    if (lane == 0) sc[s] = sum + bv[0];
  }
  __syncthreads();

  if (tid < 64) {
    float v = sc[tid];
    float m = v;
#pragma unroll
    for (int off = 32; off > 0; off >>= 1) m = fmaxf(m, __shfl_xor(m, off));
    float e = __expf(v - m);
    float ssum = e;
#pragma unroll
    for (int off = 32; off > 0; off >>= 1) ssum += __shfl_xor(ssum, off);
    float w = e / ssum;
    sc[tid] = w;
    attn_out[((size_t)b * T + t) * S + tid] = w;
  }
  __syncthreads();

  const int h4 = tid * 4;  // 256 threads * 4 = 1024 = H
  float4 acc = make_float4(0.f, 0.f, 0.f, 0.f);
  const float* eb = enc + (size_t)b * S * H;
  for (int s = 0; s < S; ++s) {
    float w = sc[s];
    float4 ev = *(const float4*)(eb + (size_t)s * H + h4);
    acc.x += w * ev.x; acc.y += w * ev.y; acc.z += w * ev.z; acc.w += w * ev.w;
  }
  *(float4*)(ctx + (size_t)b * H + h4) = acc;
}

// Build x = concat(emb[tok], ctx) : [B, 2H]
__global__ __launch_bounds__(256) void buildx_kernel(
    const float* __restrict__ emb, const int* __restrict__ tgt,
    const float* __restrict__ ctx, float* __restrict__ x, int t) {
  int i = blockIdx.x * 256 + threadIdx.x;  // < B*2H
  int b = i >> 11;        // /2048
  int c = i & 2047;
  int tok = (t == 0) ? 0 : tgt[b * T + (t - 1)];
  x[i] = (c < H) ? emb[(size_t)tok * H + c] : ctx[(size_t)b * H + (c - H)];
}

// GRU pointwise: h_new = (1-z)*n + z*h
__global__ __launch_bounds__(256) void gru_kernel(
    const float* __restrict__ gi, const float* __restrict__ gh,
    const float* __restrict__ hprev, float* __restrict__ hnew) {
  int i = blockIdx.x * 256 + threadIdx.x;  // < B*H
  int b = i >> 10;
  int h = i & 1023;
  const float* gib = gi + (size_t)b * 3 * H;
  const float* ghb = gh + (size_t)b * 3 * H;
  float ir = gib[h], iz = gib[H + h], in_ = gib[2 * H + h];
  float hr = ghb[h], hz = ghb[H + h], hn = ghb[2 * H + h];
  float r = 1.f / (1.f + __expf(-(ir + hr)));
  float z = 1.f / (1.f + __expf(-(iz + hz)));
  float n = tanhf(in_ + r * hn);
  hnew[i] = (1.f - z) * n + z * hprev[i];
}

// Log-softmax over V per batch row; writes out[b,t,:].
__global__ __launch_bounds__(256) void logsoftmax_kernel(
    const float* __restrict__ logits, float* __restrict__ out, int t) {
  __shared__ float redm[4];
  __shared__ float reds[4];
  const int b   = blockIdx.x;
  const int tid = threadIdx.x;
  const float* row = logits + (size_t)b * V;

  float m = -INFINITY;
  for (int v = tid; v < V; v += 256) m = fmaxf(m, row[v]);
#pragma unroll
  for (int off = 32; off > 0; off >>= 1) m = fmaxf(m, __shfl_xor(m, off));
  if ((tid & 63) == 0) redm[tid >> 6] = m;
  __syncthreads();
  m = fmaxf(fmaxf(redm[0], redm[1]), fmaxf(redm[2], redm[3]));

  float s = 0.f;
  for (int v = tid; v < V; v += 256) s += __expf(row[v] - m);
#pragma unroll
  for (int off = 32; off > 0; off >>= 1) s += __shfl_xor(s, off);
  if ((tid & 63) == 0) reds[tid >> 6] = s;
  __syncthreads();
  s = reds[0] + reds[1] + reds[2] + reds[3];

  float lse = m + logf(s);
  float* orow = out + ((size_t)b * T + t) * V;
  for (int v = tid; v < V; v += 256) orow[v] = row[v] - lse;
}

extern "C" void kernel_launch(void* const* d_in, const int* in_sizes, int n_in,
                              void* d_out, int out_size, void* d_ws, size_t ws_size,
                              hipStream_t stream) {
  const float* enc    = (const float*)d_in[0];   // [B,S,H]
  const float* h_init = (const float*)d_in[1];   // [1,B,H]
  const int*   tgt    = (const int*)d_in[2];     // [B,T]
  const float* emb    = (const float*)d_in[3];   // [V,H]
  const float* Wa     = (const float*)d_in[4];   // [H,H]
  const float* ba     = (const float*)d_in[5];   // [H]
  const float* Ua     = (const float*)d_in[6];   // [H,H]
  const float* bu     = (const float*)d_in[7];   // [H]
  const float* Va     = (const float*)d_in[8];   // [1,H]
  const float* bv     = (const float*)d_in[9];   // [1]
  const float* W_ih   = (const float*)d_in[10];  // [3H,2H]
  const float* W_hh   = (const float*)d_in[11];  // [3H,H]
  const float* b_ih   = (const float*)d_in[12];  // [3H]
  const float* b_hh   = (const float*)d_in[13];  // [3H]
  const float* Wout   = (const float*)d_in[14];  // [V,H]
  const float* bout   = (const float*)d_in[15];  // [V]

  float* out = (float*)d_out;
  float* ws  = (float*)d_ws;

  // Workspace layout (floats)
  float* Uk     = ws;                       // B*S*H  = 4194304
  float* h0     = Uk + (size_t)B * S * H;   // B*H
  float* h1     = h0 + (size_t)B * H;       // B*H
  float* q      = h1 + (size_t)B * H;       // B*H
  float* ctx    = q + (size_t)B * H;        // B*H
  float* x      = ctx + (size_t)B * H;      // B*2H
  float* gi     = x + (size_t)B * 2 * H;    // B*3H
  float* gh     = gi + (size_t)B * 3 * H;   // B*3H
  float* logits = gh + (size_t)B * 3 * H;   // B*V

  const size_t OFF_HT   = (size_t)B * T * V;            // log_probs size
  const size_t OFF_ATTN = OFF_HT + (size_t)B * H;       // + hT size

  // Uk = enc @ Ua^T + bu  : M=B*S=4096, N=H, K=H
  gemm_abt<<<dim3(H / BN, (B * S) / BM), 256, 0, stream>>>(
      enc, Ua, bu, Uk, B * S, H, H);

  // h0 <- encoder_hidden[0]
  hipMemcpyAsync(h0, h_init, (size_t)B * H * sizeof(float),
                 hipMemcpyDeviceToDevice, stream);

  float* hc = h0;
  float* hn = h1;
  for (int t = 0; t < T; ++t) {
    // q = h @ Wa^T + ba : M=B, N=H, K=H
    gemm_abt<<<dim3(H / BN, 1), 256, 0, stream>>>(hc, Wa, ba, q, B, H, H);
    // attention: scores, softmax, ctx; writes attentions[b,t,:]
    attn_kernel<<<B, 256, 0, stream>>>(q, Uk, Va, bv, enc, ctx,
                                       out + OFF_ATTN, t);
    // x = concat(emb[tok], ctx)
    buildx_kernel<<<(B * 2 * H) / 256, 256, 0, stream>>>(emb, tgt, ctx, x, t);
    // gi = x @ W_ih^T + b_ih : M=B, N=3H, K=2H
    gemm_abt<<<dim3(3 * H / BN, 1), 256, 0, stream>>>(x, W_ih, b_ih, gi,
                                                      B, 3 * H, 2 * H);
    // gh = h @ W_hh^T + b_hh : M=B, N=3H, K=H
    gemm_abt<<<dim3(3 * H / BN, 1), 256, 0, stream>>>(hc, W_hh, b_hh, gh,
                                                      B, 3 * H, H);
    // GRU pointwise -> hn
    gru_kernel<<<(B * H) / 256, 256, 0, stream>>>(gi, gh, hc, hn);
    // logits = hn @ Wout^T + bout : M=B, N=V, K=H
    gemm_abt<<<dim3((V + BN - 1) / BN, 1), 256, 0, stream>>>(hn, Wout, bout,
                                                             logits, B, V, H);
    // log_softmax -> out[b,t,:]
    logsoftmax_kernel<<<B, 256, 0, stream>>>(logits, out, t);
    // swap h buffers
    float* tmp = hc; hc = hn; hn = tmp;
  }

  // hT -> out (after T steps hc holds the final hidden state)
  hipMemcpyAsync(out + OFF_HT, hc, (size_t)B * H * sizeof(float),
                 hipMemcpyDeviceToDevice, stream);
}

// Round 2
// 3259.495 us; speedup vs baseline: 3.0397x; 3.0397x over previous
//
#include <hip/hip_runtime.h>
#include <hip/hip_bf16.h>
#include <math.h>

// Problem constants
#define B 64
#define S 64
#define T 15
#define H 1024
#define V 50257
#define VPAD 50304  // V padded to multiple of 64 for aligned logits rows
// SOS token = 0

typedef __attribute__((ext_vector_type(8))) short short8;
typedef __attribute__((ext_vector_type(4))) float f32x4;

// fp32 -> bf16 with round-to-nearest-even (manual, no header dependency)
__device__ __forceinline__ short f2bf(float x) {
  unsigned u = __float_as_uint(x);
  u += 0x7fffu + ((u >> 16) & 1u);
  return (short)(u >> 16);
}

__device__ __forceinline__ float fast_sigmoid(float x) {
  return 1.f / (1.f + __expf(-x));
}
__device__ __forceinline__ float fast_tanh(float x) {
  x = fminf(15.f, fmaxf(-15.f, x));
  float e = __expf(2.f * x);
  return (e - 1.f) / (e + 1.f);
}

// ---------------------------------------------------------------------------
// Generic MFMA GEMM: C[M,N] = A[M,K](fp32) @ Bt[N,K](fp32)^T  (+bias) (+addC)
// A, Bt are fp32 in global; converted to bf16 during LDS staging.
// Split-B: rows n >= Nsplit come from Bt2 (row n-Nsplit, ldb2), bias2 likewise.
// M multiple of 64, K multiple of 64, N ragged OK.
// 256 threads = 4 waves; wave w computes rows [16w,16w+16) x 64 cols.
// ---------------------------------------------------------------------------
__global__ __launch_bounds__(256) void gemm_mfma(
    const float* __restrict__ A, int lda,
    const float* __restrict__ Bt, int ldb,
    const float* __restrict__ Bt2, int ldb2, int Nsplit,
    const float* __restrict__ bias, const float* __restrict__ bias2,
    const float* __restrict__ addC,
    float* __restrict__ C, int ldc,
    int M, int N, int K) {
  __shared__ short As[64][72];  // +8 shorts pad: 2-way bank aliasing only (free)
  __shared__ short Bs[64][72];
  const int tid  = threadIdx.x;
  const int bm   = blockIdx.y * 64;
  const int bn   = blockIdx.x * 64;
  const int srow = tid >> 2;         // staging row 0..63
  const int scol = (tid & 3) << 4;   // staging col 0,16,32,48
  const int wv   = tid >> 6;         // wave 0..3
  const int lane = tid & 63;
  const int fr   = lane & 15;        // fragment row/col index
  const int qd   = lane >> 4;        // quad 0..3

  f32x4 acc[4] = {};

  const float* arow = A + (size_t)(bm + srow) * lda + scol;
  const int    bro  = bn + srow;
  const bool   bvalid = (bro < N);
  const float* brow =
      (bro >= Nsplit) ? (Bt2 + (size_t)(bro - Nsplit) * ldb2 + scol)
                      : (Bt + (size_t)bro * ldb + scol);

  union PK { short8 v; short s[8]; };

  for (int k0 = 0; k0 < K; k0 += 64) {
    // ---- stage A tile (64x64 fp32 -> bf16) ----
    {
      const float4* p = (const float4*)(arow + k0);
      float4 v0 = p[0], v1 = p[1], v2 = p[2], v3 = p[3];
      PK lo, hi;
      lo.s[0] = f2bf(v0.x); lo.s[1] = f2bf(v0.y); lo.s[2] = f2bf(v0.z); lo.s[3] = f2bf(v0.w);
      lo.s[4] = f2bf(v1.x); lo.s[5] = f2bf(v1.y); lo.s[6] = f2bf(v1.z); lo.s[7] = f2bf(v1.w);
      hi.s[0] = f2bf(v2.x); hi.s[1] = f2bf(v2.y); hi.s[2] = f2bf(v2.z); hi.s[3] = f2bf(v2.w);
      hi.s[4] = f2bf(v3.x); hi.s[5] = f2bf(v3.y); hi.s[6] = f2bf(v3.z); hi.s[7] = f2bf(v3.w);
      *(short8*)&As[srow][scol]     = lo.v;
      *(short8*)&As[srow][scol + 8] = hi.v;
    }
    // ---- stage B tile ----
    {
      float4 v0, v1, v2, v3;
      if (bvalid) {
        const float4* p = (const float4*)(brow + k0);
        v0 = p[0]; v1 = p[1]; v2 = p[2]; v3 = p[3];
      } else {
        v0 = v1 = v2 = v3 = make_float4(0.f, 0.f, 0.f, 0.f);
      }
      PK lo, hi;
      lo.s[0] = f2bf(v0.x); lo.s[1] = f2bf(v0.y); lo.s[2] = f2bf(v0.z); lo.s[3] = f2bf(v0.w);
      lo.s[4] = f2bf(v1.x); lo.s[5] = f2bf(v1.y); lo.s[6] = f2bf(v1.z); lo.s[7] = f2bf(v1.w);
      hi.s[0] = f2bf(v2.x); hi.s[1] = f2bf(v2.y); hi.s[2] = f2bf(v2.z); hi.s[3] = f2bf(v2.w);
      hi.s[4] = f2bf(v3.x); hi.s[5] = f2bf(v3.y); hi.s[6] = f2bf(v3.z); hi.s[7] = f2bf(v3.w);
      *(short8*)&Bs[srow][scol]     = lo.v;
      *(short8*)&Bs[srow][scol + 8] = hi.v;
    }
    __syncthreads();
#pragma unroll
    for (int ks = 0; ks < 64; ks += 32) {
      short8 af = *(const short8*)&As[wv * 16 + fr][ks + qd * 8];
#pragma unroll
      for (int f = 0; f < 4; ++f) {
        short8 bf = *(const short8*)&Bs[f * 16 + fr][ks + qd * 8];
        acc[f] = __builtin_amdgcn_mfma_f32_16x16x32_bf16(af, bf, acc[f], 0, 0, 0);
      }
    }
    __syncthreads();
  }

  // epilogue: C row = bm + 16*wv + 4*qd + r ; col = bn + 16*f + fr
  const int rowb = bm + wv * 16 + (qd << 2);
#pragma unroll
  for (int f = 0; f < 4; ++f) {
    const int col = bn + f * 16 + fr;
    if (col < N) {
      float bval = 0.f;
      if (bias) bval = (col < Nsplit) ? bias[col] : bias2[col - Nsplit];
#pragma unroll
      for (int r = 0; r < 4; ++r) {
        float v = acc[f][r] + bval;
        if (addC) v += addC[(size_t)(rowb + r) * ldc + col];
        C[(size_t)(rowb + r) * ldc + col] = v;
      }
    }
  }
}

// ---------------------------------------------------------------------------
// E[r=t*B+b, :] = emb[input_token(t,b), :]   (teacher-forced tokens, fp32)
// ---------------------------------------------------------------------------
__global__ __launch_bounds__(256) void buildE_kernel(
    const float* __restrict__ emb, const int* __restrict__ tgt,
    float* __restrict__ E) {
  const int r = blockIdx.x;      // 0..959
  const int t = r >> 6;
  const int b = r & 63;
  const int tok = (t == 0) ? 0 : tgt[b * T + (t - 1)];
  const float4* src = (const float4*)(emb + (size_t)tok * H);
  float4* dst = (float4*)(E + (size_t)r * H);
  dst[threadIdx.x] = src[threadIdx.x];  // 256 * 4 = 1024 = H
}

// ---------------------------------------------------------------------------
// Attention step: one block per batch row.
// scores[s] = Va . tanh(q[b] + Uk[b,s]) + bv; w = softmax; ctx = w @ enc[b]
// q lives in qgh rows (stride 4096, cols 0..1023).
// ---------------------------------------------------------------------------
__global__ __launch_bounds__(256) void attn_kernel(
    const float* __restrict__ qgh, const float* __restrict__ Uk,
    const float* __restrict__ Va, const float* __restrict__ bv,
    const float* __restrict__ enc, float* __restrict__ ctx,
    float* __restrict__ attn_out, int t) {
  __shared__ float qs[H];
  __shared__ float vas[H];
  __shared__ float sc[S];
  const int b   = blockIdx.x;
  const int tid = threadIdx.x;

  for (int i = tid; i < H; i += 256) {
    qs[i]  = qgh[(size_t)b * 4096 + i];
    vas[i] = Va[i];
  }
  __syncthreads();

  const int wave = tid >> 6;
  const int lane = tid & 63;
  for (int s = wave; s < S; s += 4) {
    const float* uk = Uk + ((size_t)(b * S + s)) * H;
    float sum = 0.f;
#pragma unroll 4
    for (int h = lane; h < H; h += 64) {
      sum += vas[h] * fast_tanh(qs[h] + uk[h]);
    }
#pragma unroll
    for (int off = 32; off > 0; off >>= 1) sum += __shfl_down(sum, off);
    if (lane == 0) sc[s] = sum + bv[0];
  }
  __syncthreads();

  if (tid < 64) {
    float v = sc[tid];
    float m = v;
#pragma unroll
    for (int off = 32; off > 0; off >>= 1) m = fmaxf(m, __shfl_xor(m, off));
    float e = __expf(v - m);
    float ssum = e;
#pragma unroll
    for (int off = 32; off > 0; off >>= 1) ssum += __shfl_xor(ssum, off);
    float w = e / ssum;
    sc[tid] = w;
    attn_out[((size_t)b * T + t) * S + tid] = w;
  }
  __syncthreads();

  const int h4 = tid * 4;  // 256 threads * 4 = 1024 = H
  float4 acc = make_float4(0.f, 0.f, 0.f, 0.f);
  const float* eb = enc + (size_t)b * S * H;
#pragma unroll 4
  for (int s = 0; s < S; ++s) {
    float w = sc[s];
    float4 ev = *(const float4*)(eb + (size_t)s * H + h4);
    acc.x += w * ev.x; acc.y += w * ev.y; acc.z += w * ev.z; acc.w += w * ev.w;
  }
  *(float4*)(ctx + (size_t)b * H + h4) = acc;
}

// ---------------------------------------------------------------------------
// GRU pointwise. gi rows stride 3072; gh = qgh cols [1024..4095] stride 4096.
// ---------------------------------------------------------------------------
__global__ __launch_bounds__(256) void gru_kernel(
    const float* __restrict__ gi, const float* __restrict__ qgh,
    const float* __restrict__ hprev, float* __restrict__ hnew) {
  const int i = blockIdx.x * 256 + threadIdx.x;  // < B*H
  const int b = i >> 10;
  const int h = i & 1023;
  const float* gib = gi + (size_t)b * 3072;
  const float* ghb = qgh + (size_t)b * 4096 + 1024;
  float ir = gib[h], iz = gib[H + h], in_ = gib[2 * H + h];
  float hr = ghb[h], hz = ghb[H + h], hn = ghb[2 * H + h];
  float r = fast_sigmoid(ir + hr);
  float z = fast_sigmoid(iz + hz);
  float n = fast_tanh(in_ + r * hn);
  hnew[i] = (1.f - z) * n + z * hprev[i];
}

// ---------------------------------------------------------------------------
// Log-softmax over V per batch row (logits rows padded to VPAD, aligned).
// ---------------------------------------------------------------------------
__global__ __launch_bounds__(512) void logsoftmax_kernel(
    const float* __restrict__ logits, float* __restrict__ out, int t) {
  __shared__ float redm[8];
  __shared__ float reds[8];
  const int b   = blockIdx.x;
  const int tid = threadIdx.x;
  const float* row = logits + (size_t)b * VPAD;
  const float4* row4 = (const float4*)row;
  const int N4 = V >> 2;  // 12564 full float4s; element 50256 is the tail

  float m = -INFINITY;
  for (int i = tid; i < N4; i += 512) {
    float4 v = row4[i];
    m = fmaxf(m, fmaxf(fmaxf(v.x, v.y), fmaxf(v.z, v.w)));
  }
  if (tid == 0) m = fmaxf(m, row[V - 1]);
#pragma unroll
  for (int off = 32; off > 0; off >>= 1) m = fmaxf(m, __shfl_xor(m, off));
  if ((tid & 63) == 0) redm[tid >> 6] = m;
  __syncthreads();
  m = redm[0];
#pragma unroll
  for (int i = 1; i < 8; ++i) m = fmaxf(m, redm[i]);

  float s = 0.f;
  for (int i = tid; i < N4; i += 512) {
    float4 v = row4[i];
    s += __expf(v.x - m) + __expf(v.y - m) + __expf(v.z - m) + __expf(v.w - m);
  }
  if (tid == 0) s += __expf(row[V - 1] - m);
#pragma unroll
  for (int off = 32; off > 0; off >>= 1) s += __shfl_xor(s, off);
  if ((tid & 63) == 0) reds[tid >> 6] = s;
  __syncthreads();
  s = reds[0];
#pragma unroll
  for (int i = 1; i < 8; ++i) s += reds[i];

  const float lse = m + logf(s);
  float* orow = out + ((size_t)b * T + t) * V;
  for (int v = tid; v < V; v += 512) orow[v] = row[v] - lse;
}

// ---------------------------------------------------------------------------
extern "C" void kernel_launch(void* const* d_in, const int* in_sizes, int n_in,
                              void* d_out, int out_size, void* d_ws, size_t ws_size,
                              hipStream_t stream) {
  const float* enc    = (const float*)d_in[0];   // [B,S,H]
  const float* h_init = (const float*)d_in[1];   // [1,B,H]
  const int*   tgt    = (const int*)d_in[2];     // [B,T]
  const float* emb    = (const float*)d_in[3];   // [V,H]
  const float* Wa     = (const float*)d_in[4];   // [H,H]
  const float* ba     = (const float*)d_in[5];   // [H]
  const float* Ua     = (const float*)d_in[6];   // [H,H]
  const float* bu     = (const float*)d_in[7];   // [H]
  const float* Va     = (const float*)d_in[8];   // [1,H]
  const float* bv     = (const float*)d_in[9];   // [1]
  const float* W_ih   = (const float*)d_in[10];  // [3H,2H]
  const float* W_hh   = (const float*)d_in[11];  // [3H,H]
  const float* b_ih   = (const float*)d_in[12];  // [3H]
  const float* b_hh   = (const float*)d_in[13];  // [3H]
  const float* Wout   = (const float*)d_in[14];  // [V,H]
  const float* bout   = (const float*)d_in[15];  // [V]

  float* out = (float*)d_out;
  float* ws  = (float*)d_ws;

  const int BIG = 1 << 30;

  // Workspace layout (floats)
  float* Uk     = ws;                            // 4096*1024
  float* E      = Uk + (size_t)4096 * 1024;      // 960*1024
  float* gi_e   = E + (size_t)960 * 1024;        // 960*3072
  float* qgh    = gi_e + (size_t)960 * 3072;     // 64*4096
  float* ctx    = qgh + (size_t)64 * 4096;       // 64*1024
  float* gi     = ctx + (size_t)64 * 1024;       // 64*3072
  float* ha     = gi + (size_t)64 * 3072;        // 64*1024
  float* hb     = ha + (size_t)64 * 1024;        // 64*1024
  float* logits = hb + (size_t)64 * 1024;        // 64*VPAD

  const size_t OFF_HT   = (size_t)B * T * V;
  const size_t OFF_ATTN = OFF_HT + (size_t)B * H;

  // ---- one-time setup ----
  // E = gathered teacher-forced embeddings (fp32)
  buildE_kernel<<<T * B, 256, 0, stream>>>(emb, tgt, E);
  // Uk = enc @ Ua^T + bu : M=4096, N=1024, K=1024
  gemm_mfma<<<dim3(16, 64), 256, 0, stream>>>(
      enc, H, Ua, H, Ua, H, BIG, bu, nullptr, nullptr, Uk, H, 4096, H, H);
  // gi_e = E @ W_ih[:, :H]^T + b_ih : M=960, N=3072, K=1024 (ldb=2H)
  gemm_mfma<<<dim3(48, 15), 256, 0, stream>>>(
      E, H, W_ih, 2 * H, W_ih, 2 * H, BIG, b_ih, nullptr, nullptr,
      gi_e, 3 * H, 960, 3 * H, H);

  const float* hc = h_init;  // step 0 reads encoder_hidden[0] directly
  for (int t = 0; t < T; ++t) {
    float* hn = (t & 1) ? hb : ha;
    // qgh = h @ [Wa; W_hh]^T + [ba; b_hh] : M=64, N=4096, K=1024 (split-B)
    gemm_mfma<<<dim3(64, 1), 256, 0, stream>>>(
        hc, H, Wa, H, W_hh, H, H, ba, b_hh, nullptr, qgh, 4096, 64, 4096, H);
    // attention -> ctx, attn_out[b,t,:]
    attn_kernel<<<B, 256, 0, stream>>>(qgh, Uk, Va, bv, enc, ctx,
                                       out + OFF_ATTN, t);
    // gi = ctx @ W_ih[:, H:]^T + gi_e[t] : M=64, N=3072, K=1024
    gemm_mfma<<<dim3(48, 1), 256, 0, stream>>>(
        ctx, H, W_ih + H, 2 * H, W_ih + H, 2 * H, BIG, nullptr, nullptr,
        gi_e + (size_t)t * 64 * 3072, gi, 3 * H, 64, 3 * H, H);
    // GRU pointwise -> hn
    gru_kernel<<<(B * H) / 256, 256, 0, stream>>>(gi, qgh, hc, hn);
    // logits = hn @ Wout^T + bout : M=64, N=V, K=1024 (ldc=VPAD)
    gemm_mfma<<<dim3((V + 63) / 64, 1), 256, 0, stream>>>(
        hn, H, Wout, H, Wout, H, BIG, bout, nullptr, nullptr,
        logits, VPAD, 64, V, H);
    // log_softmax -> out[b,t,:]
    logsoftmax_kernel<<<B, 512, 0, stream>>>(logits, out, t);
    hc = hn;
  }

  // hT
  hipMemcpyAsync(out + OFF_HT, hc, (size_t)B * H * sizeof(float),
                 hipMemcpyDeviceToDevice, stream);
}